// Round 3
// baseline (1042.635 us; speedup 1.0000x reference)
//
#include <hip/hip_runtime.h>
#include <cstddef>

// ---------------------------------------------------------------------------
// GAT 3-layer pipeline, round 3.
// - GEMMs: MFMA bf16 hi/lo split (3 mfma / logical), fused [W | lw] per layer.
// - h stored bf16 (halves gather traffic in aggregation).
// - attention scalars computed as act @ (W. att) — no h scan.
// ---------------------------------------------------------------------------

typedef __bf16 bf16x8 __attribute__((ext_vector_type(8)));
typedef float floatx4 __attribute__((ext_vector_type(4)));

__device__ __forceinline__ unsigned short bf16_rn(float f) {
    unsigned int u = __float_as_uint(f);
    u += 0x7FFF + ((u >> 16) & 1);
    return (unsigned short)(u >> 16);
}
__device__ __forceinline__ float bf16_tof(unsigned short h) {
    return __uint_as_float(((unsigned int)h) << 16);
}

// ---------------- CSR build ----------------

__global__ void degree_kernel(const int* __restrict__ dst, int* __restrict__ deg, int E) {
    int e = blockIdx.x * 256 + threadIdx.x;
    if (e < E) atomicAdd(&deg[dst[e]], 1);
}

__global__ __launch_bounds__(1024) void scan_kernel(const int* __restrict__ deg,
                                                    int* __restrict__ off, int n) {
    __shared__ int wsum[16];
    __shared__ int carry_s;
    int tid = threadIdx.x, lane = tid & 63, wid = tid >> 6;
    if (tid == 0) { carry_s = 0; off[0] = 0; }
    __syncthreads();
    for (int base = 0; base < n; base += 1024) {
        int i = base + tid;
        int v = (i < n) ? deg[i] : 0;
        int s = v;
        #pragma unroll
        for (int d = 1; d < 64; d <<= 1) {
            int t = __shfl_up(s, d, 64);
            if (lane >= d) s += t;
        }
        if (lane == 63) wsum[wid] = s;
        __syncthreads();
        if (wid == 0) {
            int wv = (lane < 16) ? wsum[lane] : 0;
            #pragma unroll
            for (int d = 1; d < 16; d <<= 1) {
                int t = __shfl_up(wv, d, 64);
                if (lane >= d) wv += t;
            }
            if (lane < 16) wsum[lane] = wv;
        }
        __syncthreads();
        int prev = (wid > 0) ? wsum[wid - 1] : 0;
        int inc = carry_s + prev + s;
        if (i < n) off[i + 1] = inc;
        int chunk_total = wsum[15];
        __syncthreads();
        if (tid == 0) carry_s += chunk_total;
        __syncthreads();
    }
}

__global__ void scatter_kernel(const int* __restrict__ src, const int* __restrict__ dst,
                               const int* __restrict__ off, int* __restrict__ cursor,
                               int* __restrict__ csrc, int E) {
    int e = blockIdx.x * 256 + threadIdx.x;
    if (e < E) {
        int d = dst[e];
        int p = off[d] + atomicAdd(&cursor[d], 1);
        csrc[p] = src[e];
    }
}

// ---------------- conversions ----------------

__global__ void convert_split_kernel(const float* __restrict__ in,
                                     ushort* __restrict__ hi, ushort* __restrict__ lo,
                                     int n4) {
    int i = blockIdx.x * 256 + threadIdx.x;
    if (i >= n4) return;
    float4 v = ((const float4*)in)[i];
    ushort4 h, l;
    h.x = bf16_rn(v.x); l.x = bf16_rn(v.x - bf16_tof(h.x));
    h.y = bf16_rn(v.y); l.y = bf16_rn(v.y - bf16_tof(h.y));
    h.z = bf16_rn(v.z); l.z = bf16_rn(v.z - bf16_tof(h.z));
    h.w = bf16_rn(v.w); l.w = bf16_rn(v.w - bf16_tof(h.w));
    ((ushort4*)hi)[i] = h;
    ((ushort4*)lo)[i] = l;
}

// W fp32 [K,Ncols] -> transposed bf16 hi/lo written at rows [roff, roff+Ncols) of Bcat[*,K]
__global__ void convert_w_kernel(const float* __restrict__ W,
                                 ushort* __restrict__ Th, ushort* __restrict__ Tl,
                                 int K, int Ncols, int roff) {
    int idx = blockIdx.x * 256 + threadIdx.x;
    if (idx >= K * Ncols) return;
    int k = idx / Ncols, n = idx - k * Ncols;
    float v = W[idx];
    unsigned short h = bf16_rn(v);
    Th[(size_t)(n + roff) * K + k] = h;
    Tl[(size_t)(n + roff) * K + k] = bf16_rn(v - bf16_tof(h));
}

// fold attention vectors through W: vsd[k][h] = sum_c W[k,h*C+c]*as[h,c]; [k][H+h] for ad
__global__ void fold_att_kernel(const float* __restrict__ W,
                                const float* __restrict__ as_, const float* __restrict__ ad_,
                                float* __restrict__ vsd, int K, int C, int H) {
    int idx = blockIdx.x * 256 + threadIdx.x;
    if (idx >= K * H) return;
    int k = idx / H, hh = idx - k * H;
    const float* wp = W + (size_t)k * (H * C) + hh * C;
    float s = 0.f, d = 0.f;
    for (int c = 0; c < C; c++) {
        float w = wp[c];
        s += w * as_[hh * C + c];
        d += w * ad_[hh * C + c];
    }
    vsd[k * 2 * H + hh] = s;
    vsd[k * 2 * H + H + hh] = d;
}

// attention scalars: asrc/adst [N,4] = act(fp32 from hi/lo) @ vsd[256, 8]
__global__ __launch_bounds__(256) void attdot_kernel(
    const ushort* __restrict__ act_hi, const ushort* __restrict__ act_lo,
    const float* __restrict__ vsd,
    float* __restrict__ asrc, float* __restrict__ adst, int n)
{
    __shared__ float vs[8 * 256];  // vs[j*256 + k]
    int tid = threadIdx.x;
    for (int i = tid; i < 2048; i += 256) vs[(i & 7) * 256 + (i >> 3)] = vsd[i];
    __syncthreads();
    int wid = tid >> 6, lane = tid & 63;
    int node = blockIdx.x * 4 + wid;
    if (node >= n) return;
    const ushort* ph = act_hi + (size_t)node * 256;
    const ushort* pl = act_lo + (size_t)node * 256;
    float acc[8] = {};
    #pragma unroll
    for (int t = 0; t < 4; t++) {
        int c = lane + t * 64;
        float v = bf16_tof(ph[c]) + bf16_tof(pl[c]);
        #pragma unroll
        for (int j = 0; j < 8; j++) acc[j] += v * vs[j * 256 + c];
    }
    #pragma unroll
    for (int o = 32; o > 0; o >>= 1)
        #pragma unroll
        for (int j = 0; j < 8; j++) acc[j] += __shfl_down(acc[j], o, 64);
    if (lane == 0) {
        #pragma unroll
        for (int j = 0; j < 4; j++) asrc[node * 4 + j] = acc[j];
        #pragma unroll
        for (int j = 0; j < 4; j++) adst[node * 4 + j] = acc[4 + j];
    }
}

// ---------------- MFMA GEMM: [O1 | O2] = A[MxK] * Bcat[KxN] ------------------
// A bf16 hi/lo [M,K]; Bcat pre-transposed bf16 hi/lo [N,K]. cols < n1 -> O1
// (no bias), cols >= n1 -> O2 (+bias2). Outputs bf16. n1 % 128 == 0.

#define LDS_STRIDE 40  // ushorts per row (80 B): frag reads <=2-way (free)

__global__ __launch_bounds__(256) void gemm_mfma_kernel(
    const ushort* __restrict__ Ah, const ushort* __restrict__ Al,
    const ushort* __restrict__ Bh, const ushort* __restrict__ Bl,
    ushort* __restrict__ O1, int n1, ushort* __restrict__ O2,
    const float* __restrict__ bias2,
    int M, int N, int K)
{
    __shared__ ushort lds[4 * 128 * LDS_STRIDE];
    const int AH = 0, AL = 128 * LDS_STRIDE, BH = 2 * 128 * LDS_STRIDE, BL = 3 * 128 * LDS_STRIDE;

    int tid = threadIdx.x;
    int bm = blockIdx.x * 128;
    int bn = blockIdx.y * 128;
    int lane = tid & 63, wid = tid >> 6;
    int wm = (wid >> 1) * 64;
    int wn = (wid & 1) * 64;
    int fr = lane & 15;
    int q  = lane >> 4;

    floatx4 acc[4][4] = {};

    for (int k0 = 0; k0 < K; k0 += 32) {
        __syncthreads();
        #pragma unroll
        for (int t = 0; t < 2; ++t) {
            int idx = tid + t * 256;
            int row = idx >> 2, c = idx & 3;
            size_t goff = (size_t)(bm + row) * K + k0 + c * 8;
            float4 va = make_float4(0.f, 0.f, 0.f, 0.f), vl = va;
            if (bm + row < M) {
                va = *(const float4*)(Ah + goff);
                vl = *(const float4*)(Al + goff);
            }
            *(float4*)(&lds[AH + row * LDS_STRIDE + c * 8]) = va;
            *(float4*)(&lds[AL + row * LDS_STRIDE + c * 8]) = vl;
            size_t boff = (size_t)(bn + row) * K + k0 + c * 8;
            *(float4*)(&lds[BH + row * LDS_STRIDE + c * 8]) = *(const float4*)(Bh + boff);
            *(float4*)(&lds[BL + row * LDS_STRIDE + c * 8]) = *(const float4*)(Bl + boff);
        }
        __syncthreads();

        bf16x8 ah[4], al[4], bh[4], bl[4];
        #pragma unroll
        for (int i = 0; i < 4; ++i) {
            int r = wm + i * 16 + fr;
            ah[i] = *(const bf16x8*)(&lds[AH + r * LDS_STRIDE + q * 8]);
            al[i] = *(const bf16x8*)(&lds[AL + r * LDS_STRIDE + q * 8]);
        }
        #pragma unroll
        for (int j = 0; j < 4; ++j) {
            int r = wn + j * 16 + fr;
            bh[j] = *(const bf16x8*)(&lds[BH + r * LDS_STRIDE + q * 8]);
            bl[j] = *(const bf16x8*)(&lds[BL + r * LDS_STRIDE + q * 8]);
        }
        #pragma unroll
        for (int i = 0; i < 4; ++i)
            #pragma unroll
            for (int j = 0; j < 4; ++j) {
                acc[i][j] = __builtin_amdgcn_mfma_f32_16x16x32_bf16(ah[i], bh[j], acc[i][j], 0, 0, 0);
                acc[i][j] = __builtin_amdgcn_mfma_f32_16x16x32_bf16(ah[i], bl[j], acc[i][j], 0, 0, 0);
                acc[i][j] = __builtin_amdgcn_mfma_f32_16x16x32_bf16(al[i], bh[j], acc[i][j], 0, 0, 0);
            }
    }

    int n2 = N - n1;
    #pragma unroll
    for (int i = 0; i < 4; ++i) {
        #pragma unroll
        for (int r = 0; r < 4; ++r) {
            int grow = bm + wm + i * 16 + q * 4 + r;
            if (grow < M) {
                #pragma unroll
                for (int j = 0; j < 4; ++j) {
                    int gcol = bn + wn + j * 16 + fr;
                    float v = acc[i][j][r];
                    if (gcol < n1) {
                        O1[(size_t)grow * n1 + gcol] = bf16_rn(v);
                    } else {
                        v += bias2[gcol - n1];
                        O2[(size_t)grow * n2 + (gcol - n1)] = bf16_rn(v);
                    }
                }
            }
        }
    }
}

// ---------------- aggregation layers 0/1 (h bf16 [N,256]) --------------------

__global__ __launch_bounds__(256) void agg01_kernel(
    const ushort* __restrict__ h,    // [N,256] bf16
    const float* __restrict__ asrc, const float* __restrict__ adst,
    const int* __restrict__ off, const int* __restrict__ csrc,
    const ushort* __restrict__ lin,  // [N,256] bf16 (bias applied in GEMM)
    const float* __restrict__ bias,  // [256]
    ushort* __restrict__ out_hi, ushort* __restrict__ out_lo,
    int n)
{
    int d = blockIdx.x;
    if (d >= n) return;
    int tid = threadIdx.x;
    int head = tid >> 6;
    float a_d = adst[d * 4 + head];
    int s0 = off[d], s1 = off[d + 1];

    float m = -INFINITY;
    for (int i = s0; i < s1; i++) {
        int s = csrc[i];
        float e = asrc[s * 4 + head] + a_d;
        e = (e > 0.f) ? e : 0.2f * e;
        m = fmaxf(m, e);
    }
    float denom = 0.f, acc = 0.f;
    for (int i = s0; i < s1; i++) {
        int s = csrc[i];
        float e = asrc[s * 4 + head] + a_d;
        e = (e > 0.f) ? e : 0.2f * e;
        float w = __expf(e - m);
        denom += w;
        acc += w * bf16_tof(h[(size_t)s * 256 + tid]);
    }
    float val = acc / (denom + 1e-16f);
    val += bias[tid] + bf16_tof(lin[(size_t)d * 256 + tid]);
    val = (val > 0.f) ? val : (__expf(val) - 1.f);  // ELU
    unsigned short hv = bf16_rn(val);
    out_hi[(size_t)d * 256 + tid] = hv;
    out_lo[(size_t)d * 256 + tid] = bf16_rn(val - bf16_tof(hv));
}

// ---------------- aggregation layer 2 (h bf16 [N,512], mean heads) -----------

__global__ __launch_bounds__(256) void agg2_kernel(
    const ushort* __restrict__ h,    // [N,512] bf16
    const float* __restrict__ asrc, const float* __restrict__ adst,
    const int* __restrict__ off, const int* __restrict__ csrc,
    const ushort* __restrict__ lin,  // [N,128] bf16 (lb2 applied in GEMM)
    const float* __restrict__ bias,  // [128]
    float* __restrict__ out,         // [N,128]
    int n)
{
    int d = blockIdx.x;
    if (d >= n) return;
    int tid = threadIdx.x;
    int h0 = tid >> 7;
    float ad_a = adst[d * 4 + h0];
    float ad_b = adst[d * 4 + h0 + 2];
    int s0 = off[d], s1 = off[d + 1];

    float ma = -INFINITY, mb = -INFINITY;
    for (int i = s0; i < s1; i++) {
        int s = csrc[i];
        float ea = asrc[s * 4 + h0] + ad_a;     ea = (ea > 0.f) ? ea : 0.2f * ea;
        float eb = asrc[s * 4 + h0 + 2] + ad_b; eb = (eb > 0.f) ? eb : 0.2f * eb;
        ma = fmaxf(ma, ea);
        mb = fmaxf(mb, eb);
    }
    float da = 0.f, db = 0.f, acca = 0.f, accb = 0.f;
    for (int i = s0; i < s1; i++) {
        int s = csrc[i];
        float ea = asrc[s * 4 + h0] + ad_a;     ea = (ea > 0.f) ? ea : 0.2f * ea;
        float eb = asrc[s * 4 + h0 + 2] + ad_b; eb = (eb > 0.f) ? eb : 0.2f * eb;
        float wa = __expf(ea - ma), wb = __expf(eb - mb);
        da += wa; db += wb;
        acca += wa * bf16_tof(h[(size_t)s * 512 + tid]);
        accb += wb * bf16_tof(h[(size_t)s * 512 + 256 + tid]);
    }
    float va = acca / (da + 1e-16f);
    float vb = accb / (db + 1e-16f);

    __shared__ float vals[512];
    vals[tid] = va;
    vals[tid + 256] = vb;
    __syncthreads();
    if (tid < 128) {
        float s = 0.25f * (vals[tid] + vals[128 + tid] + vals[256 + tid] + vals[384 + tid]);
        s += bias[tid] + bf16_tof(lin[(size_t)d * 128 + tid]);
        out[(size_t)d * 128 + tid] = s;
    }
}

// ---------------------------------------------------------------------------

extern "C" void kernel_launch(void* const* d_in, const int* in_sizes, int n_in,
                              void* d_out, int out_size, void* d_ws, size_t ws_size,
                              hipStream_t stream)
{
    const float* x   = (const float*)d_in[0];
    const int*   ei  = (const int*)d_in[1];
    const float* W0  = (const float*)d_in[2];
    const float* as0 = (const float*)d_in[3];
    const float* ad0 = (const float*)d_in[4];
    const float* b0  = (const float*)d_in[5];
    const float* lw0 = (const float*)d_in[6];
    const float* lb0 = (const float*)d_in[7];
    const float* W1  = (const float*)d_in[8];
    const float* as1 = (const float*)d_in[9];
    const float* ad1 = (const float*)d_in[10];
    const float* b1  = (const float*)d_in[11];
    const float* lw1 = (const float*)d_in[12];
    const float* lb1 = (const float*)d_in[13];
    const float* W2  = (const float*)d_in[14];
    const float* as2 = (const float*)d_in[15];
    const float* ad2 = (const float*)d_in[16];
    const float* b2  = (const float*)d_in[17];
    const float* lw2 = (const float*)d_in[18];
    const float* lb2 = (const float*)d_in[19];
    float* out = (float*)d_out;

    const int N = in_sizes[0] / 256;
    const int E = in_sizes[1] / 2;
    const int* esrc = ei;
    const int* edst = ei + E;

    // ---- workspace layout (~140 MB) ----
    char* p = (char*)d_ws;
    ushort* act_hi = (ushort*)p; p += (size_t)N * 256 * 2;
    ushort* act_lo = (ushort*)p; p += (size_t)N * 256 * 2;
    ushort* h      = (ushort*)p; p += (size_t)N * 512 * 2;   // bf16
    ushort* lin    = (ushort*)p; p += (size_t)N * 256 * 2;   // bf16
    float*  asrc   = (float*)p;  p += (size_t)N * 4 * 4;
    float*  adst   = (float*)p;  p += (size_t)N * 4 * 4;
    ushort* B0h = (ushort*)p; p += (size_t)512 * 256 * 2;
    ushort* B0l = (ushort*)p; p += (size_t)512 * 256 * 2;
    ushort* B1h = (ushort*)p; p += (size_t)512 * 256 * 2;
    ushort* B1l = (ushort*)p; p += (size_t)512 * 256 * 2;
    ushort* B2h = (ushort*)p; p += (size_t)640 * 256 * 2;
    ushort* B2l = (ushort*)p; p += (size_t)640 * 256 * 2;
    float* vsd0 = (float*)p; p += 256 * 8 * 4;
    float* vsd1 = (float*)p; p += 256 * 8 * 4;
    float* vsd2 = (float*)p; p += 256 * 8 * 4;
    int* deg    = (int*)p;
    int* off    = deg + N;
    int* cursor = off + N + 1;
    int* csrc   = cursor + N;

    // ---- CSR build ----
    hipMemsetAsync(deg, 0, sizeof(int) * (size_t)(3 * N + 1), stream);
    int egrid = (E + 255) / 256;
    degree_kernel<<<egrid, 256, 0, stream>>>(edst, deg, E);
    scan_kernel<<<1, 1024, 0, stream>>>(deg, off, N);
    scatter_kernel<<<egrid, 256, 0, stream>>>(esrc, edst, off, cursor, csrc, E);

    // ---- weight prep ----
    int wg64k = (256 * 256 + 255) / 256;
    convert_w_kernel<<<wg64k, 256, 0, stream>>>(W0,  B0h, B0l, 256, 256, 0);
    convert_w_kernel<<<wg64k, 256, 0, stream>>>(lw0, B0h, B0l, 256, 256, 256);
    convert_w_kernel<<<wg64k, 256, 0, stream>>>(W1,  B1h, B1l, 256, 256, 0);
    convert_w_kernel<<<wg64k, 256, 0, stream>>>(lw1, B1h, B1l, 256, 256, 256);
    convert_w_kernel<<<2 * wg64k, 256, 0, stream>>>(W2, B2h, B2l, 256, 512, 0);
    convert_w_kernel<<<(256 * 128 + 255) / 256, 256, 0, stream>>>(lw2, B2h, B2l, 256, 128, 512);
    fold_att_kernel<<<4, 256, 0, stream>>>(W0, as0, ad0, vsd0, 256, 64, 4);
    fold_att_kernel<<<4, 256, 0, stream>>>(W1, as1, ad1, vsd1, 256, 64, 4);
    fold_att_kernel<<<4, 256, 0, stream>>>(W2, as2, ad2, vsd2, 256, 128, 4);

    // ---- x -> bf16 hi/lo ----
    int n4 = N * 256 / 4;
    convert_split_kernel<<<(n4 + 255) / 256, 256, 0, stream>>>(x, act_hi, act_lo, n4);

    int gm = (N + 127) / 128;
    int gatt = (N + 3) / 4;

    // ---- layer 0 ----
    gemm_mfma_kernel<<<dim3(gm, 4), 256, 0, stream>>>(act_hi, act_lo, B0h, B0l, h, 256, lin, lb0, N, 512, 256);
    attdot_kernel<<<gatt, 256, 0, stream>>>(act_hi, act_lo, vsd0, asrc, adst, N);
    agg01_kernel<<<N, 256, 0, stream>>>(h, asrc, adst, off, csrc, lin, b0, act_hi, act_lo, N);

    // ---- layer 1 ----
    gemm_mfma_kernel<<<dim3(gm, 4), 256, 0, stream>>>(act_hi, act_lo, B1h, B1l, h, 256, lin, lb1, N, 512, 256);
    attdot_kernel<<<gatt, 256, 0, stream>>>(act_hi, act_lo, vsd1, asrc, adst, N);
    agg01_kernel<<<N, 256, 0, stream>>>(h, asrc, adst, off, csrc, lin, b1, act_hi, act_lo, N);

    // ---- layer 2 ----
    gemm_mfma_kernel<<<dim3(gm, 5), 256, 0, stream>>>(act_hi, act_lo, B2h, B2l, h, 512, lin, lb2, N, 640, 256);
    attdot_kernel<<<gatt, 256, 0, stream>>>(act_hi, act_lo, vsd2, asrc, adst, N);
    agg2_kernel<<<N, 256, 0, stream>>>(h, asrc, adst, off, csrc, lin, b2, out, N);
}

// Round 4
// 811.635 us; speedup vs baseline: 1.2846x; 1.2846x over previous
//
#include <hip/hip_runtime.h>
#include <cstddef>

// ---------------------------------------------------------------------------
// GAT 3-layer pipeline, round 4.
// - GEMMs: MFMA bf16 hi/lo split, global_load_lds(16B) staging + XOR swizzle.
// - Aggregation: wave-per-node, single pass (global-amax softmax bound).
// - attention scalars via act @ (W.att) fold.
// ---------------------------------------------------------------------------

typedef __bf16 bf16x8 __attribute__((ext_vector_type(8)));
typedef float floatx4 __attribute__((ext_vector_type(4)));

__device__ __forceinline__ unsigned short bf16_rn(float f) {
    unsigned int u = __float_as_uint(f);
    u += 0x7FFF + ((u >> 16) & 1);
    return (unsigned short)(u >> 16);
}
__device__ __forceinline__ float bf16_tof(unsigned short h) {
    return __uint_as_float(((unsigned int)h) << 16);
}

// ---------------- CSR build ----------------

__global__ void degree_kernel(const int* __restrict__ dst, int* __restrict__ deg, int E) {
    int e = blockIdx.x * 256 + threadIdx.x;
    if (e < E) atomicAdd(&deg[dst[e]], 1);
}

__global__ __launch_bounds__(1024) void scan_kernel(const int* __restrict__ deg,
                                                    int* __restrict__ off, int n) {
    __shared__ int wsum[16];
    __shared__ int carry_s;
    int tid = threadIdx.x, lane = tid & 63, wid = tid >> 6;
    if (tid == 0) { carry_s = 0; off[0] = 0; }
    __syncthreads();
    for (int base = 0; base < n; base += 1024) {
        int i = base + tid;
        int v = (i < n) ? deg[i] : 0;
        int s = v;
        #pragma unroll
        for (int d = 1; d < 64; d <<= 1) {
            int t = __shfl_up(s, d, 64);
            if (lane >= d) s += t;
        }
        if (lane == 63) wsum[wid] = s;
        __syncthreads();
        if (wid == 0) {
            int wv = (lane < 16) ? wsum[lane] : 0;
            #pragma unroll
            for (int d = 1; d < 16; d <<= 1) {
                int t = __shfl_up(wv, d, 64);
                if (lane >= d) wv += t;
            }
            if (lane < 16) wsum[lane] = wv;
        }
        __syncthreads();
        int prev = (wid > 0) ? wsum[wid - 1] : 0;
        int inc = carry_s + prev + s;
        if (i < n) off[i + 1] = inc;
        int chunk_total = wsum[15];
        __syncthreads();
        if (tid == 0) carry_s += chunk_total;
        __syncthreads();
    }
}

__global__ void scatter_kernel(const int* __restrict__ src, const int* __restrict__ dst,
                               const int* __restrict__ off, int* __restrict__ cursor,
                               int* __restrict__ csrc, int E) {
    int e = blockIdx.x * 256 + threadIdx.x;
    if (e < E) {
        int d = dst[e];
        int p = off[d] + atomicAdd(&cursor[d], 1);
        csrc[p] = src[e];
    }
}

// ---------------- conversions ----------------

__global__ void convert_split_kernel(const float* __restrict__ in,
                                     ushort* __restrict__ hi, ushort* __restrict__ lo,
                                     int n4) {
    int i = blockIdx.x * 256 + threadIdx.x;
    if (i >= n4) return;
    float4 v = ((const float4*)in)[i];
    ushort4 h, l;
    h.x = bf16_rn(v.x); l.x = bf16_rn(v.x - bf16_tof(h.x));
    h.y = bf16_rn(v.y); l.y = bf16_rn(v.y - bf16_tof(h.y));
    h.z = bf16_rn(v.z); l.z = bf16_rn(v.z - bf16_tof(h.z));
    h.w = bf16_rn(v.w); l.w = bf16_rn(v.w - bf16_tof(h.w));
    ((ushort4*)hi)[i] = h;
    ((ushort4*)lo)[i] = l;
}

// W fp32 [K,Ncols] -> transposed bf16 hi/lo at rows [roff, roff+Ncols) of Bcat[*,K]
__global__ void convert_w_kernel(const float* __restrict__ W,
                                 ushort* __restrict__ Th, ushort* __restrict__ Tl,
                                 int K, int Ncols, int roff) {
    int idx = blockIdx.x * 256 + threadIdx.x;
    if (idx >= K * Ncols) return;
    int k = idx / Ncols, n = idx - k * Ncols;
    float v = W[idx];
    unsigned short h = bf16_rn(v);
    Th[(size_t)(n + roff) * K + k] = h;
    Tl[(size_t)(n + roff) * K + k] = bf16_rn(v - bf16_tof(h));
}

// fold attention vectors through W
__global__ void fold_att_kernel(const float* __restrict__ W,
                                const float* __restrict__ as_, const float* __restrict__ ad_,
                                float* __restrict__ vsd, int K, int C, int H) {
    int idx = blockIdx.x * 256 + threadIdx.x;
    if (idx >= K * H) return;
    int k = idx / H, hh = idx - k * H;
    const float* wp = W + (size_t)k * (H * C) + hh * C;
    float s = 0.f, d = 0.f;
    for (int c = 0; c < C; c++) {
        float w = wp[c];
        s += w * as_[hh * C + c];
        d += w * ad_[hh * C + c];
    }
    vsd[k * 2 * H + hh] = s;
    vsd[k * 2 * H + H + hh] = d;
}

// attention scalars: asrc/adst [N,4] = act @ vsd[256,8]
__global__ __launch_bounds__(256) void attdot_kernel(
    const ushort* __restrict__ act_hi, const ushort* __restrict__ act_lo,
    const float* __restrict__ vsd,
    float* __restrict__ asrc, float* __restrict__ adst, int n)
{
    __shared__ float vs[8 * 256];
    int tid = threadIdx.x;
    for (int i = tid; i < 2048; i += 256) vs[(i & 7) * 256 + (i >> 3)] = vsd[i];
    __syncthreads();
    int wid = tid >> 6, lane = tid & 63;
    int node = blockIdx.x * 4 + wid;
    if (node >= n) return;
    const ushort* ph = act_hi + (size_t)node * 256;
    const ushort* pl = act_lo + (size_t)node * 256;
    float acc[8] = {};
    #pragma unroll
    for (int t = 0; t < 4; t++) {
        int c = lane + t * 64;
        float v = bf16_tof(ph[c]) + bf16_tof(pl[c]);
        #pragma unroll
        for (int j = 0; j < 8; j++) acc[j] += v * vs[j * 256 + c];
    }
    #pragma unroll
    for (int o = 32; o > 0; o >>= 1)
        #pragma unroll
        for (int j = 0; j < 8; j++) acc[j] += __shfl_down(acc[j], o, 64);
    if (lane == 0) {
        #pragma unroll
        for (int j = 0; j < 4; j++) asrc[node * 4 + j] = acc[j];
        #pragma unroll
        for (int j = 0; j < 4; j++) adst[node * 4 + j] = acc[4 + j];
    }
}

// per-head global max of asrc (order-preserving uint encoding)
__global__ __launch_bounds__(256) void amax_kernel(const float* __restrict__ asrc,
                                                   unsigned int* __restrict__ amax, int n) {
    int tid = threadIdx.x;
    float4 m4 = make_float4(-1e30f, -1e30f, -1e30f, -1e30f);
    for (int i = blockIdx.x * 256 + tid; i < n; i += gridDim.x * 256) {
        float4 v = ((const float4*)asrc)[i];
        m4.x = fmaxf(m4.x, v.x); m4.y = fmaxf(m4.y, v.y);
        m4.z = fmaxf(m4.z, v.z); m4.w = fmaxf(m4.w, v.w);
    }
    #pragma unroll
    for (int o = 32; o > 0; o >>= 1) {
        m4.x = fmaxf(m4.x, __shfl_down(m4.x, o, 64));
        m4.y = fmaxf(m4.y, __shfl_down(m4.y, o, 64));
        m4.z = fmaxf(m4.z, __shfl_down(m4.z, o, 64));
        m4.w = fmaxf(m4.w, __shfl_down(m4.w, o, 64));
    }
    __shared__ float sm[4][4];
    int wid = tid >> 6, lane = tid & 63;
    if (lane == 0) { sm[wid][0] = m4.x; sm[wid][1] = m4.y; sm[wid][2] = m4.z; sm[wid][3] = m4.w; }
    __syncthreads();
    if (tid < 4) {
        float v = fmaxf(fmaxf(sm[0][tid], sm[1][tid]), fmaxf(sm[2][tid], sm[3][tid]));
        unsigned int u = __float_as_uint(v);
        u = (u >> 31) ? ~u : (u | 0x80000000u);
        atomicMax(&amax[tid], u);
    }
}

__device__ __forceinline__ float amax_decode(unsigned int u) {
    unsigned int bits = (u >> 31) ? (u & 0x7FFFFFFFu) : ~u;
    return __uint_as_float(bits);
}

// ---------------- MFMA GEMM: [O1 | O2] = A[MxK] * Bcat^T ---------------------
// BM=BN=128, BK=32, 256 thr = 4 waves (each 64x64). global_load_lds staging,
// XOR chunk swizzle (chunk ^= (row>>1)&3) keeps ds_read_b128 conflict-free.

#define TS 32  // ushorts per LDS row (64 B, unpadded; swizzle handles banks)

__global__ __launch_bounds__(256) void gemm_mfma_kernel(
    const ushort* __restrict__ Ah, const ushort* __restrict__ Al,
    const ushort* __restrict__ Bh, const ushort* __restrict__ Bl,
    ushort* __restrict__ O1, int n1, ushort* __restrict__ O2,
    const float* __restrict__ bias2,
    int M, int N, int K)
{
    __shared__ ushort lds[4 * 128 * TS];  // 32 KB
    int tid = threadIdx.x;
    int bm = blockIdx.x * 128;
    int bn = blockIdx.y * 128;
    int lane = tid & 63, wv = tid >> 6;
    int wm = (wv >> 1) * 64;
    int wn = (wv & 1) * 64;
    int fr = lane & 15;
    int q  = lane >> 4;

    // staging role: wave wv owns tile wv (0=AH,1=AL,2=BH,3=BL)
    const ushort* gsrc = (wv == 0) ? Ah : (wv == 1) ? Al : (wv == 2) ? Bh : Bl;
    int gbrow = (wv < 2) ? bm : bn;
    int srow = lane >> 2;                      // row within 16-row slab
    int gch  = (lane & 3) ^ ((srow >> 1) & 3); // global chunk for this lane's slot

    // frag LDS offsets (loop-invariant; swizzled)
    int offA[4], offB[4];
    #pragma unroll
    for (int i = 0; i < 4; ++i) {
        int ra = wm + i * 16 + fr;
        offA[i] = ra * TS + ((q ^ ((ra >> 1) & 3)) * 8);
        int rb = wn + i * 16 + fr;
        offB[i] = rb * TS + ((q ^ ((rb >> 1) & 3)) * 8);
    }
    const int AH = 0, AL = 128 * TS, BH = 2 * 128 * TS, BL = 3 * 128 * TS;

    floatx4 acc[4][4] = {};

    for (int k0 = 0; k0 < K; k0 += 32) {
        __syncthreads();
        #pragma unroll
        for (int j = 0; j < 8; ++j) {
            int row = j * 16 + srow;
            const ushort* g = gsrc + (size_t)(gbrow + row) * K + k0 + gch * 8;
            __builtin_amdgcn_global_load_lds(
                (const __attribute__((address_space(1))) unsigned int*)g,
                (__attribute__((address_space(3))) unsigned int*)(lds + (size_t)wv * 128 * TS + j * 16 * TS),
                16, 0, 0);
        }
        __syncthreads();

        bf16x8 ah[4], al[4], bh[4], bl[4];
        #pragma unroll
        for (int i = 0; i < 4; ++i) {
            ah[i] = *(const bf16x8*)(&lds[AH + offA[i]]);
            al[i] = *(const bf16x8*)(&lds[AL + offA[i]]);
            bh[i] = *(const bf16x8*)(&lds[BH + offB[i]]);
            bl[i] = *(const bf16x8*)(&lds[BL + offB[i]]);
        }
        #pragma unroll
        for (int i = 0; i < 4; ++i)
            #pragma unroll
            for (int j = 0; j < 4; ++j) {
                acc[i][j] = __builtin_amdgcn_mfma_f32_16x16x32_bf16(ah[i], bh[j], acc[i][j], 0, 0, 0);
                acc[i][j] = __builtin_amdgcn_mfma_f32_16x16x32_bf16(ah[i], bl[j], acc[i][j], 0, 0, 0);
                acc[i][j] = __builtin_amdgcn_mfma_f32_16x16x32_bf16(al[i], bh[j], acc[i][j], 0, 0, 0);
            }
    }

    int n2 = N - n1;
    #pragma unroll
    for (int i = 0; i < 4; ++i) {
        #pragma unroll
        for (int r = 0; r < 4; ++r) {
            int grow = bm + wm + i * 16 + q * 4 + r;
            if (grow < M) {
                #pragma unroll
                for (int j = 0; j < 4; ++j) {
                    int gcol = bn + wn + j * 16 + fr;
                    float v = acc[i][j][r];
                    if (gcol < n1) {
                        O1[(size_t)grow * n1 + gcol] = bf16_rn(v);
                    } else {
                        v += bias2[gcol - n1];
                        O2[(size_t)grow * n2 + (gcol - n1)] = bf16_rn(v);
                    }
                }
            }
        }
    }
}

// ---------------- aggregation layers 0/1: wave-per-node, single pass ---------

__global__ __launch_bounds__(256) void agg01_kernel(
    const ushort* __restrict__ h,    // [N,256] bf16
    const float* __restrict__ asrc, const float* __restrict__ adst,
    const unsigned int* __restrict__ amax,  // [4] encoded
    const int* __restrict__ off, const int* __restrict__ csrc,
    const ushort* __restrict__ lin,  // [N,256] bf16 (lb applied in GEMM)
    const float* __restrict__ bias,  // [256]
    ushort* __restrict__ out_hi, ushort* __restrict__ out_lo,
    int n)
{
    int wid = threadIdx.x >> 6, lane = threadIdx.x & 63;
    int d = blockIdx.x * 4 + wid;
    if (d >= n) return;
    int head = lane >> 4;       // 4 channels per lane, all same head
    int c0 = lane * 4;
    float a_d = adst[d * 4 + head];
    float mh = amax_decode(amax[head]) + a_d;
    float m = (mh > 0.f) ? mh : 0.2f * mh;   // >= true segment max
    int s0 = off[d], s1 = off[d + 1];

    float denom = 0.f, a0 = 0.f, a1 = 0.f, a2 = 0.f, a3 = 0.f;
    for (int i = s0; i < s1; ++i) {
        int s = csrc[i];
        float e = asrc[s * 4 + head] + a_d;
        e = (e > 0.f) ? e : 0.2f * e;
        float w = __expf(e - m);
        denom += w;
        ushort4 hv = *(const ushort4*)(h + (size_t)s * 256 + c0);
        a0 += w * bf16_tof(hv.x);
        a1 += w * bf16_tof(hv.y);
        a2 += w * bf16_tof(hv.z);
        a3 += w * bf16_tof(hv.w);
    }
    float inv = 1.f / (denom + 1e-16f);
    float4 b4 = *(const float4*)(bias + c0);
    ushort4 l4 = *(const ushort4*)(lin + (size_t)d * 256 + c0);
    float v0 = a0 * inv + b4.x + bf16_tof(l4.x);
    float v1 = a1 * inv + b4.y + bf16_tof(l4.y);
    float v2 = a2 * inv + b4.z + bf16_tof(l4.z);
    float v3 = a3 * inv + b4.w + bf16_tof(l4.w);
    v0 = (v0 > 0.f) ? v0 : (__expf(v0) - 1.f);
    v1 = (v1 > 0.f) ? v1 : (__expf(v1) - 1.f);
    v2 = (v2 > 0.f) ? v2 : (__expf(v2) - 1.f);
    v3 = (v3 > 0.f) ? v3 : (__expf(v3) - 1.f);
    ushort4 oh, ol;
    oh.x = bf16_rn(v0); ol.x = bf16_rn(v0 - bf16_tof(oh.x));
    oh.y = bf16_rn(v1); ol.y = bf16_rn(v1 - bf16_tof(oh.y));
    oh.z = bf16_rn(v2); ol.z = bf16_rn(v2 - bf16_tof(oh.z));
    oh.w = bf16_rn(v3); ol.w = bf16_rn(v3 - bf16_tof(oh.w));
    *(ushort4*)(out_hi + (size_t)d * 256 + c0) = oh;
    *(ushort4*)(out_lo + (size_t)d * 256 + c0) = ol;
}

// ---------------- aggregation layer 2: wave-per-node, mean heads -------------

__global__ __launch_bounds__(256) void agg2_kernel(
    const ushort* __restrict__ h,    // [N,512] bf16
    const float* __restrict__ asrc, const float* __restrict__ adst,
    const unsigned int* __restrict__ amax,
    const int* __restrict__ off, const int* __restrict__ csrc,
    const ushort* __restrict__ lin,  // [N,128] bf16 (lb2 applied in GEMM)
    const float* __restrict__ bias,  // [128]
    float* __restrict__ out,         // [N,128]
    int n)
{
    int wid = threadIdx.x >> 6, lane = threadIdx.x & 63;
    int d = blockIdx.x * 4 + wid;
    if (d >= n) return;
    int ha = lane >> 5;          // channels 4l..4l+3  -> head 0/1
    int hb = ha + 2;             // channels 256+4l..  -> head 2/3
    int c0 = lane * 4;
    float ad_a = adst[d * 4 + ha];
    float ad_b = adst[d * 4 + hb];
    float mha = amax_decode(amax[ha]) + ad_a;
    float mhb = amax_decode(amax[hb]) + ad_b;
    float ma = (mha > 0.f) ? mha : 0.2f * mha;
    float mb = (mhb > 0.f) ? mhb : 0.2f * mhb;
    int s0 = off[d], s1 = off[d + 1];

    float da = 0.f, db = 0.f;
    floatx4 aa = {0.f, 0.f, 0.f, 0.f}, ab = {0.f, 0.f, 0.f, 0.f};
    for (int i = s0; i < s1; ++i) {
        int s = csrc[i];
        float ea = asrc[s * 4 + ha] + ad_a;
        float eb = asrc[s * 4 + hb] + ad_b;
        ea = (ea > 0.f) ? ea : 0.2f * ea;
        eb = (eb > 0.f) ? eb : 0.2f * eb;
        float wa = __expf(ea - ma), wb = __expf(eb - mb);
        da += wa; db += wb;
        ushort4 va = *(const ushort4*)(h + (size_t)s * 512 + c0);
        ushort4 vb = *(const ushort4*)(h + (size_t)s * 512 + 256 + c0);
        aa[0] += wa * bf16_tof(va.x); aa[1] += wa * bf16_tof(va.y);
        aa[2] += wa * bf16_tof(va.z); aa[3] += wa * bf16_tof(va.w);
        ab[0] += wb * bf16_tof(vb.x); ab[1] += wb * bf16_tof(vb.y);
        ab[2] += wb * bf16_tof(vb.z); ab[3] += wb * bf16_tof(vb.w);
    }
    float ia = 1.f / (da + 1e-16f), ib = 1.f / (db + 1e-16f);
    float s4[4];
    #pragma unroll
    for (int j = 0; j < 4; ++j) s4[j] = aa[j] * ia + ab[j] * ib;  // head pair partial sum
    float p4[4];
    #pragma unroll
    for (int j = 0; j < 4; ++j) p4[j] = __shfl_xor(s4[j], 32, 64);
    if (lane < 32) {
        float4 b4 = *(const float4*)(bias + c0);
        ushort4 l4 = *(const ushort4*)(lin + (size_t)d * 128 + c0);
        float4 o;
        o.x = 0.25f * (s4[0] + p4[0]) + b4.x + bf16_tof(l4.x);
        o.y = 0.25f * (s4[1] + p4[1]) + b4.y + bf16_tof(l4.y);
        o.z = 0.25f * (s4[2] + p4[2]) + b4.z + bf16_tof(l4.z);
        o.w = 0.25f * (s4[3] + p4[3]) + b4.w + bf16_tof(l4.w);
        *(float4*)(out + (size_t)d * 128 + c0) = o;
    }
}

// ---------------------------------------------------------------------------

extern "C" void kernel_launch(void* const* d_in, const int* in_sizes, int n_in,
                              void* d_out, int out_size, void* d_ws, size_t ws_size,
                              hipStream_t stream)
{
    const float* x   = (const float*)d_in[0];
    const int*   ei  = (const int*)d_in[1];
    const float* W0  = (const float*)d_in[2];
    const float* as0 = (const float*)d_in[3];
    const float* ad0 = (const float*)d_in[4];
    const float* b0  = (const float*)d_in[5];
    const float* lw0 = (const float*)d_in[6];
    const float* lb0 = (const float*)d_in[7];
    const float* W1  = (const float*)d_in[8];
    const float* as1 = (const float*)d_in[9];
    const float* ad1 = (const float*)d_in[10];
    const float* b1  = (const float*)d_in[11];
    const float* lw1 = (const float*)d_in[12];
    const float* lb1 = (const float*)d_in[13];
    const float* W2  = (const float*)d_in[14];
    const float* as2 = (const float*)d_in[15];
    const float* ad2 = (const float*)d_in[16];
    const float* b2  = (const float*)d_in[17];
    const float* lw2 = (const float*)d_in[18];
    const float* lb2 = (const float*)d_in[19];
    float* out = (float*)d_out;

    const int N = in_sizes[0] / 256;
    const int E = in_sizes[1] / 2;
    const int* esrc = ei;
    const int* edst = ei + E;

    // ---- workspace layout ----
    char* p = (char*)d_ws;
    ushort* act_hi = (ushort*)p; p += (size_t)N * 256 * 2;
    ushort* act_lo = (ushort*)p; p += (size_t)N * 256 * 2;
    ushort* h      = (ushort*)p; p += (size_t)N * 512 * 2;
    ushort* lin    = (ushort*)p; p += (size_t)N * 256 * 2;
    float*  asrc   = (float*)p;  p += (size_t)N * 4 * 4;
    float*  adst   = (float*)p;  p += (size_t)N * 4 * 4;
    ushort* B0h = (ushort*)p; p += (size_t)512 * 256 * 2;
    ushort* B0l = (ushort*)p; p += (size_t)512 * 256 * 2;
    ushort* B1h = (ushort*)p; p += (size_t)512 * 256 * 2;
    ushort* B1l = (ushort*)p; p += (size_t)512 * 256 * 2;
    ushort* B2h = (ushort*)p; p += (size_t)640 * 256 * 2;
    ushort* B2l = (ushort*)p; p += (size_t)640 * 256 * 2;
    float* vsd0 = (float*)p; p += 256 * 8 * 4;
    float* vsd1 = (float*)p; p += 256 * 8 * 4;
    float* vsd2 = (float*)p; p += 256 * 8 * 4;
    unsigned int* amax = (unsigned int*)p;      // 12 slots (4 per layer)
    int* deg    = (int*)(amax + 12);
    int* off    = deg + N;
    int* cursor = off + N + 1;
    int* csrc   = cursor + N;

    // ---- zero amax + deg + off + cursor in one memset ----
    hipMemsetAsync(amax, 0, sizeof(int) * (size_t)(3 * N + 13), stream);

    // ---- CSR build ----
    int egrid = (E + 255) / 256;
    degree_kernel<<<egrid, 256, 0, stream>>>(edst, deg, E);
    scan_kernel<<<1, 1024, 0, stream>>>(deg, off, N);
    scatter_kernel<<<egrid, 256, 0, stream>>>(esrc, edst, off, cursor, csrc, E);

    // ---- weight prep ----
    int wg64k = (256 * 256 + 255) / 256;
    convert_w_kernel<<<wg64k, 256, 0, stream>>>(W0,  B0h, B0l, 256, 256, 0);
    convert_w_kernel<<<wg64k, 256, 0, stream>>>(lw0, B0h, B0l, 256, 256, 256);
    convert_w_kernel<<<wg64k, 256, 0, stream>>>(W1,  B1h, B1l, 256, 256, 0);
    convert_w_kernel<<<wg64k, 256, 0, stream>>>(lw1, B1h, B1l, 256, 256, 256);
    convert_w_kernel<<<2 * wg64k, 256, 0, stream>>>(W2, B2h, B2l, 256, 512, 0);
    convert_w_kernel<<<(256 * 128 + 255) / 256, 256, 0, stream>>>(lw2, B2h, B2l, 256, 128, 512);
    fold_att_kernel<<<4, 256, 0, stream>>>(W0, as0, ad0, vsd0, 256, 64, 4);
    fold_att_kernel<<<4, 256, 0, stream>>>(W1, as1, ad1, vsd1, 256, 64, 4);
    fold_att_kernel<<<4, 256, 0, stream>>>(W2, as2, ad2, vsd2, 256, 128, 4);

    // ---- x -> bf16 hi/lo ----
    int n4 = N * 256 / 4;
    convert_split_kernel<<<(n4 + 255) / 256, 256, 0, stream>>>(x, act_hi, act_lo, n4);

    int gm = (N + 127) / 128;
    int g4 = (N + 3) / 4;

    // ---- layer 0 ----
    gemm_mfma_kernel<<<dim3(gm, 4), 256, 0, stream>>>(act_hi, act_lo, B0h, B0l, h, 256, lin, lb0, N, 512, 256);
    attdot_kernel<<<g4, 256, 0, stream>>>(act_hi, act_lo, vsd0, asrc, adst, N);
    amax_kernel<<<32, 256, 0, stream>>>(asrc, amax + 0, N);
    agg01_kernel<<<g4, 256, 0, stream>>>(h, asrc, adst, amax + 0, off, csrc, lin, b0, act_hi, act_lo, N);

    // ---- layer 1 ----
    gemm_mfma_kernel<<<dim3(gm, 4), 256, 0, stream>>>(act_hi, act_lo, B1h, B1l, h, 256, lin, lb1, N, 512, 256);
    attdot_kernel<<<g4, 256, 0, stream>>>(act_hi, act_lo, vsd1, asrc, adst, N);
    amax_kernel<<<32, 256, 0, stream>>>(asrc, amax + 4, N);
    agg01_kernel<<<g4, 256, 0, stream>>>(h, asrc, adst, amax + 4, off, csrc, lin, b1, act_hi, act_lo, N);

    // ---- layer 2 ----
    gemm_mfma_kernel<<<dim3(gm, 5), 256, 0, stream>>>(act_hi, act_lo, B2h, B2l, h, 512, lin, lb2, N, 640, 256);
    attdot_kernel<<<g4, 256, 0, stream>>>(act_hi, act_lo, vsd2, asrc, adst, N);
    amax_kernel<<<32, 256, 0, stream>>>(asrc, amax + 8, N);
    agg2_kernel<<<g4, 256, 0, stream>>>(h, asrc, adst, amax + 8, off, csrc, lin, b2, out, N);
}